// Round 11
// baseline (112.229 us; speedup 1.0000x reference)
//
#include <hip/hip_runtime.h>
#include <stdint.h>

#define HD 512
#define NH 8
#define DH 64
#define SEQ 2048
#define BATCH 2
#define M_TOTAL (BATCH*SEQ)   // 4096
#define N_QKV (3*HD)          // 1536
#define K_DIM HD              // 512

typedef short bf16x8 __attribute__((ext_vector_type(8)));
typedef float f32x4 __attribute__((ext_vector_type(4)));
typedef uint32_t u32x2 __attribute__((ext_vector_type(2)));
typedef uint32_t u32x4 __attribute__((ext_vector_type(4)));

// q-scale: temperature 1/8 folded with log2(e) so v_exp_f32 (2^x) gives e^(s/8)
#define QSCALE 0.18033688011112042f

__device__ __forceinline__ uint16_t f2bf(float f) {
  union { float f; uint32_t u; } v; v.f = f;
  uint32_t u = v.u;
  return (uint16_t)((u + 0x7FFFu + ((u >> 16) & 1u)) >> 16);
}

__device__ __forceinline__ void gload_lds16(const void* g, void* l) {
  __builtin_amdgcn_global_load_lds(
      (const __attribute__((address_space(1))) void*)g,
      (__attribute__((address_space(3))) void*)l,
      16, 0, 0);
}

// one launch converting both x and W
__global__ void convert_all(const float* __restrict__ x, const float* __restrict__ W,
                            uint16_t* __restrict__ xb, uint16_t* __restrict__ Wb) {
  const int nx4 = M_TOTAL * K_DIM / 4;   // 524288
  const int nw4 = N_QKV * K_DIM / 4;     // 196608
  int i = blockIdx.x * 256 + threadIdx.x;
  const float* src; uint16_t* dst; int j;
  if (i < nx4) { src = x; dst = xb; j = i; }
  else { j = i - nx4; if (j >= nw4) return; src = W; dst = Wb; }
  float4 v = reinterpret_cast<const float4*>(src)[j];
  ushort4 o;
  o.x = f2bf(v.x); o.y = f2bf(v.y); o.z = f2bf(v.z); o.w = f2bf(v.w);
  reinterpret_cast<ushort4*>(dst)[j] = o;
}

// ---------------- QKV GEMM: C[4096,1536] = X[4096,512] @ W^T ----
#define BM 64
#define BN 128
#define BK 64
#define NKT (K_DIM / BK)      // 8

__global__ __launch_bounds__(256)
void qkv_gemm(const uint16_t* __restrict__ A,   // x bf16 [4096][512]
              const uint16_t* __restrict__ Bw,  // W bf16 [1536][512]
              uint16_t* __restrict__ C,         // qkv bf16 [4096][1536] (q,k parts)
              uint16_t* __restrict__ Vt) {      // [16][64][2048] bf16
  __shared__ __align__(16) uint16_t As[2][BM * BK];   // 16 KB (also V-transpose scratch)
  __shared__ __align__(16) uint16_t Bs[2][BN * BK];   // 32 KB

  const int t = threadIdx.x;
  const int lane = t & 63;
  const int w = t >> 6;
  const int l15 = lane & 15, l4 = lane >> 4;

  // XCD-aware bijective swizzle (768 blocks, 768%8==0)
  const int nbx = gridDim.x;                       // 12
  const int nwg = nbx * gridDim.y;                 // 768
  const int cpx = nwg >> 3;                        // 96
  int id = blockIdx.y * nbx + blockIdx.x;
  int wid = (id & 7) * cpx + (id >> 3);
  const int m0 = (wid / nbx) * BM;
  const int n0 = (wid % nbx) * BN;

  f32x4 acc[4][2] = {};

  auto stage = [&](int kt, int buf) {
#pragma unroll
    for (int i = 0; i < 2; ++i) {                  // A: 512 slots
      int idx = t + 256 * i;
      int row = idx >> 3, slot = idx & 7;
      int src = slot ^ (row & 7);
      gload_lds16(A + (size_t)(m0 + row) * K_DIM + kt * BK + src * 8,
                  (char*)As[buf] + idx * 16);
    }
#pragma unroll
    for (int i = 0; i < 4; ++i) {                  // B: 1024 slots
      int idx = t + 256 * i;
      int row = idx >> 3, slot = idx & 7;
      int src = slot ^ (row & 7);
      gload_lds16(Bw + (size_t)(n0 + row) * K_DIM + kt * BK + src * 8,
                  (char*)Bs[buf] + idx * 16);
    }
  };

  stage(0, 0);
  for (int kt = 0; kt < NKT; ++kt) {
    __syncthreads();                       // drains my gloads + barrier
    if (kt + 1 < NKT) stage(kt + 1, (kt + 1) & 1);
    const char* Ab = (const char*)As[kt & 1];
    const char* Bb = (const char*)Bs[kt & 1];
#pragma unroll
    for (int kk = 0; kk < 2; ++kk) {      // two K=32 sub-steps
      bf16x8 af[4], bf[2];
#pragma unroll
      for (int i = 0; i < 4; ++i) {
        int rowa = i * 16 + l15;
        int sa = (kk * 4 + l4) ^ (rowa & 7);
        af[i] = *reinterpret_cast<const bf16x8*>(Ab + rowa * 128 + sa * 16);
      }
#pragma unroll
      for (int j = 0; j < 2; ++j) {
        int rowb = w * 32 + j * 16 + l15;
        int sb = (kk * 4 + l4) ^ (rowb & 7);
        bf[j] = *reinterpret_cast<const bf16x8*>(Bb + rowb * 128 + sb * 16);
      }
#pragma unroll
      for (int i = 0; i < 4; ++i)
#pragma unroll
        for (int j = 0; j < 2; ++j)
          acc[i][j] = __builtin_amdgcn_mfma_f32_16x16x32_bf16(af[i], bf[j], acc[i][j], 0, 0, 0);
    }
  }

  // ---- epilogue ----
  const int colw = n0 + w * 32;                  // wave's 32-col slice (32-aligned)
  const int cmod = colw % 192;
  const bool isv = (cmod >= 128);                // slice entirely V
  __syncthreads();                                // LDS free: reuse As as scratch

  if (isv) {
    // transpose 64s x 32d through LDS -> coalesced 128B rows of Vt[bh][d][s]
    char* tb = (char*)As + w * 4096;             // per-wave 4 KB
#pragma unroll
    for (int i = 0; i < 4; ++i)
#pragma unroll
      for (int j = 0; j < 2; ++j) {
        uint32_t lo, hi;
        asm("v_cvt_pk_bf16_f32 %0, %1, %2" : "=v"(lo) : "v"(acc[i][j][0]), "v"(acc[i][j][1]));
        asm("v_cvt_pk_bf16_f32 %0, %1, %2" : "=v"(hi) : "v"(acc[i][j][2]), "v"(acc[i][j][3]));
        int dloc = j * 16 + l15;                 // 0..31
        int slot_s = i * 2 + (l4 >> 1);          // s>>3
        int byteoff = dloc * 128 + ((slot_s ^ (dloc & 7)) * 16) + (l4 & 1) * 8;
        u32x2 pk; pk.x = lo; pk.y = hi;
        *reinterpret_cast<u32x2*>(tb + byteoff) = pk;
      }
    int h = colw / 192;
    int d0 = cmod - 128;                          // 0 or 32
    int b = m0 >> 11;
    int sbase = m0 & (SEQ - 1);
    uint16_t* vbase = Vt + ((size_t)(b * NH + h) * DH + d0) * SEQ + sbase + (lane & 7) * 8;
#pragma unroll
    for (int p = 0; p < 4; ++p) {
      int dl = p * 8 + (lane >> 3);               // 0..31
      u32x4 rv = *reinterpret_cast<const u32x4*>(
          tb + dl * 128 + (((lane & 7) ^ (dl & 7)) * 16));
      *reinterpret_cast<u32x4*>(vbase + (size_t)dl * SEQ) = rv;
    }
  } else {
    // q (scaled) / k rows -> qkv
    float sc = ((cmod >> 6) == 0) ? QSCALE : 1.0f;
#pragma unroll
    for (int i = 0; i < 4; ++i) {
      int row = m0 + i * 16 + l4 * 4;
#pragma unroll
      for (int j = 0; j < 2; ++j) {
        int col = colw + j * 16 + l15;
#pragma unroll
        for (int jj = 0; jj < 4; ++jj)
          C[(size_t)(row + jj) * N_QKV + col] = f2bf(acc[i][j][jj] * sc);
      }
    }
  }
}

// ---------------- Flash attention, split-KV, KVBLK=64, QBLK=32/wave ----
// Block covers 128 q (4 waves x 32 q). K/V LDS reads amortize over 2 q-subblocks.
// LDS map: K0@0 K1@8192 V0@16384 V1@24576 Pl@32768 (w*4096, [32 q][64 keys] swizzled)
#define NT (SEQ / 64)          // 32 kv tiles total

__global__ __launch_bounds__(256)
void attn(const uint16_t* __restrict__ qkv, const uint16_t* __restrict__ VtG,
          float* __restrict__ Po,      // [split][16][2048][64] f32 unnormalized
          float2* __restrict__ Pml) {  // [split][16][2048] (m, l)
  __shared__ __align__(16) char SM[49152];

  const int t = threadIdx.x;
  const int lane = t & 63;
  const int w = t >> 6;
  const int l15 = lane & 15, l4 = lane >> 4;
  const int m7 = l15 & 7;
  const int bh = blockIdx.x;               // head-major: XCD bh%8 owns 2 heads' K/V
  const int b = bh >> 3, h = bh & 7;
  const int qw = blockIdx.y * 128 + w * 32;
  const int half = blockIdx.z;
  const int tph = NT / gridDim.z;
  const int t0 = half * tph;

  // Q fragments qf[j][kk] for q-subblocks j=0 (qw+l15) and j=1 (qw+16+l15)
  bf16x8 qf[2][2];
#pragma unroll
  for (int j = 0; j < 2; ++j) {
    const uint16_t* qp = qkv + (size_t)(b * SEQ + qw + j * 16 + l15) * N_QKV + h * 192;
#pragma unroll
    for (int kk = 0; kk < 2; ++kk)
      qf[j][kk] = *reinterpret_cast<const bf16x8*>(qp + kk * 32 + l4 * 8);
  }

  // ---- hoisted per-lane LDS addresses ----
  const uint32_t a0 = (uint32_t)(l15 * 128 + ((l4 ^ m7) * 16));
  const uint32_t a1 = a0 ^ 64;
  char* const plw = SM + 32768 + w * 4096;
  const char* const pp00 = plw + a0;          // j=0, kk=0
  const char* const pp01 = plw + a1;          // j=0, kk=1
  const char* const pp10 = plw + 2048 + a0;   // j=1, kk=0
  const char* const pp11 = plw + 2048 + a1;   // j=1, kk=1
  char* const pwb = plw + l15 * 128 + (l4 & 1) * 8;
  const int hh = l4 >> 1;
  char* const pw00 = pwb + (((0 + hh) ^ m7) * 16);
  char* const pw01 = pwb + (((2 + hh) ^ m7) * 16);
  char* const pw02 = pwb + (((4 + hh) ^ m7) * 16);
  char* const pw03 = pwb + (((6 + hh) ^ m7) * 16);
  char* const pw10 = pw00 + 2048;
  char* const pw11 = pw01 + 2048;
  char* const pw12 = pw02 + 2048;
  char* const pw13 = pw03 + 2048;

  // ---- staging pointers (advance by constant per tile) ----
  const int r0 = t >> 3;                   // 0..31
  const int sl8 = (t & 7) ^ (r0 & 7);
  const uint16_t* kg = qkv + (size_t)b * SEQ * N_QKV + h * 192 + 64
                     + (size_t)(t0 * 64 + r0) * N_QKV + sl8 * 8;
  const uint16_t* vg = VtG + (size_t)bh * DH * SEQ
                     + (size_t)r0 * SEQ + t0 * 64 + sl8 * 8;
  const uint32_t t16 = (uint32_t)t * 16;

  auto stage2 = [&](int buf) {
    char* dk = SM + buf * 8192 + t16;
    gload_lds16(kg, dk);
    gload_lds16(kg + 32 * N_QKV, dk + 4096);
    gload_lds16(vg, dk + 16384);
    gload_lds16(vg + 32 * SEQ, dk + 20480);
    kg += 64 * N_QKV;
    vg += 64;
  };

  f32x4 ot0[4] = {}, ot1[4] = {};          // ot{j}[f][jj] = O[d=f*16+l4*4+jj][q]
  float mrow0 = -1e30f, mrow1 = -1e30f;    // running max per q-subblock (log2 dom)
  float lrow0 = 0.0f, lrow1 = 0.0f;        // per-lane partial denominators

  stage2(0);
  for (int rel = 0; rel < tph; ++rel) {
    __syncthreads();                       // vmcnt(0) drain + barrier: tile rel ready
    if (rel + 1 < tph) stage2((rel + 1) & 1);
    const char* kb0 = SM + (rel & 1) * 8192 + a0;
    const char* kb1 = SM + (rel & 1) * 8192 + a1;

    // S^T = K @ Q^T for both q-subblocks; K-frag read once, used twice
    f32x4 s0[4] = {}, s1[4] = {};
    __builtin_amdgcn_s_setprio(1);
#pragma unroll
    for (int c = 0; c < 4; ++c) {
      bf16x8 kf0 = *reinterpret_cast<const bf16x8*>(kb0 + c * 2048);
      s0[c] = __builtin_amdgcn_mfma_f32_16x16x32_bf16(kf0, qf[0][0], s0[c], 0, 0, 0);
      s1[c] = __builtin_amdgcn_mfma_f32_16x16x32_bf16(kf0, qf[1][0], s1[c], 0, 0, 0);
      bf16x8 kf1 = *reinterpret_cast<const bf16x8*>(kb1 + c * 2048);
      s0[c] = __builtin_amdgcn_mfma_f32_16x16x32_bf16(kf1, qf[0][1], s0[c], 0, 0, 0);
      s1[c] = __builtin_amdgcn_mfma_f32_16x16x32_bf16(kf1, qf[1][1], s1[c], 0, 0, 0);
    }
    __builtin_amdgcn_s_setprio(0);

    // per-lane max over this lane's 16 keys, per q-subblock
    float pmax0 = fmaxf(fmaxf(fmaxf(s0[0][0], s0[0][1]), fmaxf(s0[0][2], s0[0][3])),
                        fmaxf(fmaxf(s0[1][0], s0[1][1]), fmaxf(s0[1][2], s0[1][3])));
    pmax0 = fmaxf(pmax0,
                  fmaxf(fmaxf(fmaxf(s0[2][0], s0[2][1]), fmaxf(s0[2][2], s0[2][3])),
                        fmaxf(fmaxf(s0[3][0], s0[3][1]), fmaxf(s0[3][2], s0[3][3]))));
    float pmax1 = fmaxf(fmaxf(fmaxf(s1[0][0], s1[0][1]), fmaxf(s1[0][2], s1[0][3])),
                        fmaxf(fmaxf(s1[1][0], s1[1][1]), fmaxf(s1[1][2], s1[1][3])));
    pmax1 = fmaxf(pmax1,
                  fmaxf(fmaxf(fmaxf(s1[2][0], s1[2][1]), fmaxf(s1[2][2], s1[2][3])),
                        fmaxf(fmaxf(s1[3][0], s1[3][1]), fmaxf(s1[3][2], s1[3][3]))));

    if (!__all((pmax0 - mrow0 <= 11.0f) && (pmax1 - mrow1 <= 11.0f))) {
      float vm0 = pmax0, vm1 = pmax1;
      vm0 = fmaxf(vm0, __shfl_xor(vm0, 16, 64));
      vm0 = fmaxf(vm0, __shfl_xor(vm0, 32, 64));
      vm1 = fmaxf(vm1, __shfl_xor(vm1, 16, 64));
      vm1 = fmaxf(vm1, __shfl_xor(vm1, 32, 64));
      float mn0 = fmaxf(mrow0, vm0), mn1 = fmaxf(mrow1, vm1);
      float d0 = mrow0 - mn0, d1 = mrow1 - mn1;
      float sc0, sc1;
      asm("v_exp_f32 %0, %1" : "=v"(sc0) : "v"(d0));
      asm("v_exp_f32 %0, %1" : "=v"(sc1) : "v"(d1));
      mrow0 = mn0; mrow1 = mn1;
#pragma unroll
      for (int f = 0; f < 4; ++f)
#pragma unroll
        for (int jj = 0; jj < 4; ++jj) { ot0[f][jj] *= sc0; ot1[f][jj] *= sc1; }
      lrow0 *= sc0; lrow1 *= sc1;
    }

    // j = 0: exp, sum, pack, store
    {
      float p[16];
#pragma unroll
      for (int c = 0; c < 4; ++c)
#pragma unroll
        for (int jj = 0; jj < 4; ++jj) {
          float arg = s0[c][jj] - mrow0;
          float e;
          asm("v_exp_f32 %0, %1" : "=v"(e) : "v"(arg));
          p[c * 4 + jj] = e;
        }
      lrow0 += ((p[0] + p[1]) + (p[2] + p[3])) + ((p[4] + p[5]) + (p[6] + p[7]))
             + ((p[8] + p[9]) + (p[10] + p[11])) + ((p[12] + p[13]) + (p[14] + p[15]));
      uint32_t lo, hi; u32x2 pk;
      asm("v_cvt_pk_bf16_f32 %0, %1, %2" : "=v"(lo) : "v"(p[0]), "v"(p[1]));
      asm("v_cvt_pk_bf16_f32 %0, %1, %2" : "=v"(hi) : "v"(p[2]), "v"(p[3]));
      pk.x = lo; pk.y = hi; *reinterpret_cast<u32x2*>(pw00) = pk;
      asm("v_cvt_pk_bf16_f32 %0, %1, %2" : "=v"(lo) : "v"(p[4]), "v"(p[5]));
      asm("v_cvt_pk_bf16_f32 %0, %1, %2" : "=v"(hi) : "v"(p[6]), "v"(p[7]));
      pk.x = lo; pk.y = hi; *reinterpret_cast<u32x2*>(pw01) = pk;
      asm("v_cvt_pk_bf16_f32 %0, %1, %2" : "=v"(lo) : "v"(p[8]), "v"(p[9]));
      asm("v_cvt_pk_bf16_f32 %0, %1, %2" : "=v"(hi) : "v"(p[10]), "v"(p[11]));
      pk.x = lo; pk.y = hi; *reinterpret_cast<u32x2*>(pw02) = pk;
      asm("v_cvt_pk_bf16_f32 %0, %1, %2" : "=v"(lo) : "v"(p[12]), "v"(p[13]));
      asm("v_cvt_pk_bf16_f32 %0, %1, %2" : "=v"(hi) : "v"(p[14]), "v"(p[15]));
      pk.x = lo; pk.y = hi; *reinterpret_cast<u32x2*>(pw03) = pk;
    }
    // j = 1
    {
      float p[16];
#pragma unroll
      for (int c = 0; c < 4; ++c)
#pragma unroll
        for (int jj = 0; jj < 4; ++jj) {
          float arg = s1[c][jj] - mrow1;
          float e;
          asm("v_exp_f32 %0, %1" : "=v"(e) : "v"(arg));
          p[c * 4 + jj] = e;
        }
      lrow1 += ((p[0] + p[1]) + (p[2] + p[3])) + ((p[4] + p[5]) + (p[6] + p[7]))
             + ((p[8] + p[9]) + (p[10] + p[11])) + ((p[12] + p[13]) + (p[14] + p[15]));
      uint32_t lo, hi; u32x2 pk;
      asm("v_cvt_pk_bf16_f32 %0, %1, %2" : "=v"(lo) : "v"(p[0]), "v"(p[1]));
      asm("v_cvt_pk_bf16_f32 %0, %1, %2" : "=v"(hi) : "v"(p[2]), "v"(p[3]));
      pk.x = lo; pk.y = hi; *reinterpret_cast<u32x2*>(pw10) = pk;
      asm("v_cvt_pk_bf16_f32 %0, %1, %2" : "=v"(lo) : "v"(p[4]), "v"(p[5]));
      asm("v_cvt_pk_bf16_f32 %0, %1, %2" : "=v"(hi) : "v"(p[6]), "v"(p[7]));
      pk.x = lo; pk.y = hi; *reinterpret_cast<u32x2*>(pw11) = pk;
      asm("v_cvt_pk_bf16_f32 %0, %1, %2" : "=v"(lo) : "v"(p[8]), "v"(p[9]));
      asm("v_cvt_pk_bf16_f32 %0, %1, %2" : "=v"(hi) : "v"(p[10]), "v"(p[11]));
      pk.x = lo; pk.y = hi; *reinterpret_cast<u32x2*>(pw12) = pk;
      asm("v_cvt_pk_bf16_f32 %0, %1, %2" : "=v"(lo) : "v"(p[12]), "v"(p[13]));
      asm("v_cvt_pk_bf16_f32 %0, %1, %2" : "=v"(hi) : "v"(p[14]), "v"(p[15]));
      pk.x = lo; pk.y = hi; *reinterpret_cast<u32x2*>(pw13) = pk;
    }

    // O^T += V @ P^T : V-frag read once, used for both q-subblocks
    bf16x8 pa00 = *reinterpret_cast<const bf16x8*>(pp00);
    bf16x8 pa01 = *reinterpret_cast<const bf16x8*>(pp01);
    bf16x8 pa10 = *reinterpret_cast<const bf16x8*>(pp10);
    bf16x8 pa11 = *reinterpret_cast<const bf16x8*>(pp11);
    __builtin_amdgcn_s_setprio(1);
#pragma unroll
    for (int f = 0; f < 4; ++f) {
      bf16x8 vf0 = *reinterpret_cast<const bf16x8*>(kb0 + 16384 + f * 2048);
      ot0[f] = __builtin_amdgcn_mfma_f32_16x16x32_bf16(vf0, pa00, ot0[f], 0, 0, 0);
      ot1[f] = __builtin_amdgcn_mfma_f32_16x16x32_bf16(vf0, pa10, ot1[f], 0, 0, 0);
      bf16x8 vf1 = *reinterpret_cast<const bf16x8*>(kb1 + 16384 + f * 2048);
      ot0[f] = __builtin_amdgcn_mfma_f32_16x16x32_bf16(vf1, pa01, ot0[f], 0, 0, 0);
      ot1[f] = __builtin_amdgcn_mfma_f32_16x16x32_bf16(vf1, pa11, ot1[f], 0, 0, 0);
    }
    __builtin_amdgcn_s_setprio(0);
  }

  // epilogue: reduce per-lane denominator partials (2 shuffles per subblock)
  lrow0 += __shfl_xor(lrow0, 16, 64);
  lrow0 += __shfl_xor(lrow0, 32, 64);
  lrow1 += __shfl_xor(lrow1, 16, 64);
  lrow1 += __shfl_xor(lrow1, 32, 64);

  // write partials: coalesced f32x4 (4 consecutive d per reg)
  float* pob0 = Po + ((size_t)(half * 16 + bh) * SEQ + qw + l15) * DH;
  float* pob1 = pob0 + 16 * DH;
#pragma unroll
  for (int f = 0; f < 4; ++f) {
    *reinterpret_cast<f32x4*>(pob0 + f * 16 + l4 * 4) = ot0[f];
    *reinterpret_cast<f32x4*>(pob1 + f * 16 + l4 * 4) = ot1[f];
  }
  if (lane < 16) {
    float2 ml; ml.x = mrow0; ml.y = lrow0;
    Pml[(size_t)(half * 16 + bh) * SEQ + qw + lane] = ml;
  } else if (lane < 32) {
    float2 ml; ml.x = mrow1; ml.y = lrow1;
    Pml[(size_t)(half * 16 + bh) * SEQ + qw + 16 + (lane & 15)] = ml;
  }
}

// ---------------- combine partials -> out[b][q][h*64+d] ----
__global__ __launch_bounds__(256)
void attn_combine(const float* __restrict__ Po, const float2* __restrict__ Pml,
                  float* __restrict__ out, int nsplit) {
  int idx = blockIdx.x * 256 + threadIdx.x;   // 16bh * 2048q * 16 d4
  int d4 = idx & 15;
  int q = (idx >> 4) & (SEQ - 1);
  int bh = idx >> 15;
  int b = bh >> 3, h = bh & 7;

  float m = -1e30f;
  for (int s = 0; s < nsplit; ++s)
    m = fmaxf(m, Pml[(size_t)(s * 16 + bh) * SEQ + q].x);
  float den = 0.0f;
  f32x4 acc = {};
  for (int s = 0; s < nsplit; ++s) {
    float2 ml = Pml[(size_t)(s * 16 + bh) * SEQ + q];
    float a = exp2f(ml.x - m);
    den += ml.y * a;
    f32x4 ov = *reinterpret_cast<const f32x4*>(
        Po + ((size_t)(s * 16 + bh) * SEQ + q) * DH + d4 * 4);
#pragma unroll
    for (int i = 0; i < 4; ++i) acc[i] += ov[i] * a;
  }
  float rden = 1.0f / den;
  f32x4 res;
#pragma unroll
  for (int i = 0; i < 4; ++i) res[i] = acc[i] * rden;
  *reinterpret_cast<f32x4*>(out + ((size_t)(b * SEQ + q) * HD) + h * 64 + d4 * 4) = res;
}

extern "C" void kernel_launch(void* const* d_in, const int* in_sizes, int n_in,
                              void* d_out, int out_size, void* d_ws, size_t ws_size,
                              hipStream_t stream) {
  const float* x = (const float*)d_in[0];
  const float* Wq = (const float*)d_in[1];
  float* out = (float*)d_out;

  uint16_t* xb = (uint16_t*)d_ws;                       // 4096*512 bf16   (4 MB)
  uint16_t* Wb = xb + (size_t)M_TOTAL * K_DIM;          // 1536*512 bf16   (1.5 MB)
  uint16_t* qkv = Wb + (size_t)N_QKV * K_DIM;           // 4096*1536 bf16  (12.6 MB)
  uint16_t* vtg = qkv + (size_t)M_TOTAL * N_QKV;        // 16*64*2048 bf16 (4 MB)
  float* Po = (float*)(vtg + (size_t)16 * DH * SEQ);    // 2*16*2048*64 f32 (16.8 MB)
  float2* Pml = (float2*)(Po + (size_t)2 * 16 * SEQ * DH);  // 2*16*2048 f32x2 (0.5 MB)
  size_t base = (size_t)((char*)Po - (char*)d_ws);
  size_t per_split = (size_t)16 * SEQ * DH * 4 + (size_t)16 * SEQ * 8;
  int nsplit = (ws_size >= base + 2 * per_split) ? 2 : 1;

  convert_all<<<(M_TOTAL * K_DIM / 4 + N_QKV * K_DIM / 4 + 255) / 256, 256, 0, stream>>>(
      x, Wq, xb, Wb);

  dim3 g1(N_QKV / BN, M_TOTAL / BM);
  qkv_gemm<<<g1, 256, 0, stream>>>(xb, Wb, qkv, vtg);

  dim3 g2(BATCH * NH, SEQ / 128, nsplit);
  attn<<<g2, 256, 0, stream>>>(qkv, vtg, Po, Pml);

  attn_combine<<<(16 * SEQ * 16) / 256, 256, 0, stream>>>(Po, Pml, out, nsplit);
}